// Round 2
// baseline (124.788 us; speedup 1.0000x reference)
//
#include <hip/hip_runtime.h>

// Problem constants (fixed by the reference)
#define NB   8
#define C    128
#define H    112
#define W    112
#define HW   (H * W)
#define HO   56
#define WO   56
#define KK   9      // 3x3 = 9 sigma channels
#define WAVES 16
#define CPW  8      // channels per wave = C / WAVES
#define NPAIR (C / 2)            // 64 channel pairs
#define PPW  (CPW / 2)           // 4 pairs per wave
#define WPW  (PPW * 81)          // packed v2f weights per wave = 324

typedef float v2f __attribute__((ext_vector_type(2)));

// Packed fp32 fma -> v_pk_fma_f32 on gfx950 (VOP3P); falls back to 2x v_fma.
__device__ inline v2f pkfma(v2f a, v2f b, v2f c) {
    return __builtin_elementwise_fma(a, b, c);
}

// ---------------------------------------------------------------------------
// Single fused kernel: PASA downsample, register-resident x, TWO output
// rows per block, weight prep folded in as per-wave LDS staging.
//
// Grid = 8 * 28 = 224 blocks (1/CU, single scheduling round).
// Per block: input rows 4hb-1..4hb+3 (5 rows for 2 output rows). ALL 40 v2f
// row-loads are issued up-front so the entire HBM read stream is in flight
// during weight staging + Phase A (kernel is BW-bound: ~51 MB unique reads
// since the harness' 256 MiB workspace poison evicts x from L3 each iter).
//
// Weight staging: each wave packs its own 4 channel-pairs (324 v2f, BN scale
// folded) into a private LDS slab -- intra-wave producer/consumer only, so
// no extra __syncthreads; global reads overlap the x-load latency; Phase A
// reads are wave-uniform ds_read_b64 broadcasts (conflict-free, LDS pipe is
// idle otherwise). BN shift applied by the reduce threads (one rsqrtf each).
// This removes the separate prep kernel launch (~4-5 us serialized).
//
// __launch_bounds__(1024, 4): 1 block/CU, VGPR cap 128 (no spill).
// ---------------------------------------------------------------------------
__global__ __launch_bounds__(1024, 4)
void pasa_main(const float* __restrict__ x,
               const float* __restrict__ cw,
               const float* __restrict__ bw,
               const float* __restrict__ bb,
               const float* __restrict__ bm,
               const float* __restrict__ bv,
               float* __restrict__ out) {
    __shared__ v2f   wlds[WAVES][WPW];        // 41.5 KB packed scaled weights
    __shared__ float part[WAVES * KK * 64];   // 36 KB
    __shared__ float sig[KK * 57];            // padded row stride

    // XCD swizzle: grid 224 = 8 XCDs * 28; bid%8 = n -> same-n blocks (which
    // share seam rows 4hb+3 = 4(hb+1)-1) land on the same XCD's L2.
    const int bid  = blockIdx.x;
    const int n    = bid & 7;
    const int hb   = bid >> 3;                 // 0..27
    const int tid  = threadIdx.x;
    const int lane = tid & 63;
    const int wv   = __builtin_amdgcn_readfirstlane(tid >> 6);  // wave-uniform
    const int wo   = lane < WO ? lane : (WO - 1);               // clamp tail

    // Rows for ho0 = 2*hb (top reflect -1 -> 1 only at hb==0) and ho1 = 2*hb+1.
    const int r0 = (hb == 0) ? 1 : (4 * hb - 1);
    const int r1 = 4 * hb;
    const int r2 = 4 * hb + 1;
    const int r3 = 4 * hb + 2;
    const int r4 = 4 * hb + 3;                 // max 111, no bottom reflect

    const float* xn = x + (size_t)n * C * HW;
    const int p0 = wv * PPW;   // first channel-pair of this wave

    // ---- Issue ALL x row-loads up front (40 v2f in flight) ----------------
    v2f va[PPW][3], vb[PPW][3];     // rows r0..r2 (half 0)
    v2f ta[PPW][2], tb[PPW][2];     // rows r3..r4 (half 1)
#pragma unroll
    for (int p = 0; p < PPW; ++p) {
        const float* xa = xn + (size_t)(2 * (p0 + p)) * HW + 2 * wo;
        const float* xb = xa + HW;
        va[p][0] = *(const v2f*)(xa + r0 * W);
        va[p][1] = *(const v2f*)(xa + r1 * W);
        va[p][2] = *(const v2f*)(xa + r2 * W);
        vb[p][0] = *(const v2f*)(xb + r0 * W);
        vb[p][1] = *(const v2f*)(xb + r1 * W);
        vb[p][2] = *(const v2f*)(xb + r2 * W);
        ta[p][0] = *(const v2f*)(xa + r3 * W);
        ta[p][1] = *(const v2f*)(xa + r4 * W);
        tb[p][0] = *(const v2f*)(xb + r3 * W);
        tb[p][1] = *(const v2f*)(xb + r4 * W);
    }

    // ---- Per-wave weight staging (overlaps x-load latency; no barrier) ----
    // Layout: wlds[wv][p*81 + kh*27 + k*3 + kw] = {cw_a, cw_b} * scale[k]
    for (int i = lane; i < WPW; i += 64) {
        const int p   = i / 81;
        const int rem = i % 81;
        const int kh  = rem / 27;
        const int rr  = rem % 27;
        const int k   = rr / 3;
        const int kw  = rr % 3;
        const float scale = bw[k] * rsqrtf(bv[k] + 1e-5f);
        const int ca = 2 * (p0 + p);
        v2f wv2;
        wv2.x = cw[((k * C + ca)     * 3 + kh) * 3 + kw] * scale;
        wv2.y = cw[((k * C + ca + 1) * 3 + kh) * 3 + kw] * scale;
        wlds[wv][i] = wv2;
    }

    float* on_base = out + (size_t)n * C * (HO * WO);

#pragma unroll
    for (int half = 0; half < 2; ++half) {
        // ---- Phase A: packed partial sigma over the 4 channel pairs -------
        v2f acc[KK];
#pragma unroll
        for (int k = 0; k < KK; ++k) acc[k] = (v2f){0.0f, 0.0f};

#pragma unroll
        for (int p = 0; p < PPW; ++p) {
#pragma unroll
            for (int kh = 0; kh < 3; ++kh) {
                v2f t1 = { va[p][kh].x, vb[p][kh].x };
                v2f t2 = { va[p][kh].y, vb[p][kh].y };
                v2f t0;
                t0.x = __shfl_up(t2.x, 1);   // lane0 keeps own = reflect(-1)=col1
                t0.y = __shfl_up(t2.y, 1);
                const v2f* wr = &wlds[wv][p * 81 + kh * 27];  // wave-uniform
#pragma unroll
                for (int k = 0; k < KK; ++k)
                    acc[k] = pkfma(t2, wr[3 * k + 2],
                              pkfma(t1, wr[3 * k + 1],
                              pkfma(t0, wr[3 * k + 0], acc[k])));
            }
        }

#pragma unroll
        for (int k = 0; k < KK; ++k)
            part[(wv * KK + k) * 64 + lane] = acc[k].x + acc[k].y;
        __syncthreads();

        // ---- Cross-wave reduce + BN shift + clamp -------------------------
        if (tid < KK * WO) {
            const int k  = tid / WO;
            const int w_ = tid % WO;
            float s = 0.0f;
#pragma unroll
            for (int w2 = 0; w2 < WAVES; ++w2) s += part[(w2 * KK + k) * 64 + w_];
            const float scale = bw[k] * rsqrtf(bv[k] + 1e-5f);
            s += bb[k] - bm[k] * scale;        // shift (scale already in weights)
            s = fmaxf(s, 1e-4f);
            sig[k * 57 + w_] = s;
        }
        __syncthreads();

        // ---- Normalize into registers (per-lane, lane = wo) ---------------
        float sg[KK];
        float tot = 0.0f;
#pragma unroll
        for (int k = 0; k < KK; ++k) { sg[k] = sig[k * 57 + wo]; tot += sg[k]; }
        const float inv = 1.0f / tot;
#pragma unroll
        for (int k = 0; k < KK; ++k) sg[k] *= inv;

        // ---- Phase B: apply adaptive filter from REGISTERS (packed) -------
        const int ho = 2 * hb + half;
        float* on = on_base + (size_t)ho * WO;
#pragma unroll
        for (int p = 0; p < PPW; ++p) {
            v2f o = (v2f){0.0f, 0.0f};
#pragma unroll
            for (int kh = 0; kh < 3; ++kh) {
                v2f t1 = { va[p][kh].x, vb[p][kh].x };
                v2f t2 = { va[p][kh].y, vb[p][kh].y };
                v2f t0;
                t0.x = __shfl_up(t2.x, 1);
                t0.y = __shfl_up(t2.y, 1);
                v2f s0 = { sg[kh * 3 + 0], sg[kh * 3 + 0] };
                v2f s1 = { sg[kh * 3 + 1], sg[kh * 3 + 1] };
                v2f s2 = { sg[kh * 3 + 2], sg[kh * 3 + 2] };
                o = pkfma(t2, s2, pkfma(t1, s1, pkfma(t0, s0, o)));
            }
            if (lane < WO) {
                const int ci = 2 * (p0 + p);
                // Output is never re-read: don't pollute L2 (seam-row reuse).
                __builtin_nontemporal_store(o.x, on + (size_t)ci * (HO * WO) + lane);
                __builtin_nontemporal_store(o.y, on + (size_t)(ci + 1) * (HO * WO) + lane);
            }
        }

        // ---- Rotate register rows for half 1: (r2, r3, r4) ----------------
        if (half == 0) {
#pragma unroll
            for (int p = 0; p < PPW; ++p) {
                va[p][0] = va[p][2]; va[p][1] = ta[p][0]; va[p][2] = ta[p][1];
                vb[p][0] = vb[p][2]; vb[p][1] = tb[p][0]; vb[p][2] = tb[p][1];
            }
        }
    }
}

extern "C" void kernel_launch(void* const* d_in, const int* in_sizes, int n_in,
                              void* d_out, int out_size, void* d_ws, size_t ws_size,
                              hipStream_t stream) {
    const float* x   = (const float*)d_in[0];
    const float* cw  = (const float*)d_in[1];
    const float* bw  = (const float*)d_in[2];
    const float* bb  = (const float*)d_in[3];
    const float* bm  = (const float*)d_in[4];
    const float* bv  = (const float*)d_in[5];
    float* out = (float*)d_out;
    (void)d_ws; (void)ws_size;

    // Single launch: weight prep folded into pasa_main (per-wave LDS staging).
    pasa_main<<<NB * (HO / 2), 1024, 0, stream>>>(x, cw, bw, bb, bm, bv, out);
}

// Round 3
// 106.669 us; speedup vs baseline: 1.1699x; 1.1699x over previous
//
#include <hip/hip_runtime.h>

// Problem constants (fixed by the reference)
#define NB   8
#define C    128
#define H    112
#define W    112
#define HW   (H * W)
#define HO   56
#define WO   56
#define KK   9      // 3x3 = 9 sigma channels
#define WAVES 16
#define PPW  4                   // channel-pairs per wave
#define NPAIR (C / 2)            // 64 channel pairs
#define WPK_ELEMS (NPAIR * 81)   // float2 count: [cip][kh][k*3+kw]
#define SHIFT_OFF (WPK_ELEMS * 2)  // float offset of shift[9] in ws

typedef float v2f __attribute__((ext_vector_type(2)));

// Packed fp32 fma -> v_pk_fma_f32 on gfx950 (VOP3P); falls back to 2x v_fma.
__device__ inline v2f pkfma(v2f a, v2f b, v2f c) {
    return __builtin_elementwise_fma(a, b, c);
}

// ---------------------------------------------------------------------------
// Kernel 0: weights -> d_ws as channel-PAIR packed float2, BN scale folded.
// (Known-good from the 110.2 us baseline; fusing this into main caused the
// round-2 spill regression, so it stays a separate tiny launch.)
// ---------------------------------------------------------------------------
__global__ void pasa_prep(const float* __restrict__ cw,
                          const float* __restrict__ bw,
                          const float* __restrict__ bb,
                          const float* __restrict__ bm,
                          const float* __restrict__ bv,
                          float* __restrict__ ws) {
    int idx = blockIdx.x * 256 + threadIdx.x;
    if (idx < WPK_ELEMS) {
        int cip = idx / 81;
        int rem = idx % 81;
        int kh = rem / 27;
        int r2 = rem % 27;
        int k  = r2 / 3;
        int kw = r2 % 3;
        float scale = bw[k] * rsqrtf(bv[k] + 1e-5f);
        int ca = 2 * cip, cb = 2 * cip + 1;
        ws[2 * idx + 0] = cw[((k * C + ca) * 3 + kh) * 3 + kw] * scale;
        ws[2 * idx + 1] = cw[((k * C + cb) * 3 + kh) * 3 + kw] * scale;
    } else if (idx < WPK_ELEMS + KK) {
        int k = idx - WPK_ELEMS;
        float scale = bw[k] * rsqrtf(bv[k] + 1e-5f);
        ws[SHIFT_OFF + k] = bb[k] - bm[k] * scale;
    }
}

// ---------------------------------------------------------------------------
// Kernel 1: fused PASA downsample, TWO blocks per CU for phase overlap.
//
// Round-2 rocprof showed the 1-block/CU register-resident design runs at only
// ~3 TB/s effective: each CU alternates {load burst | barrier | 504-thread
// reduce | apply} with the memory pipe idle half the time. Fix: 32 waves/CU
// (2 x 16-wave blocks) so phases of independent blocks overlap. That needs
// <=64 VGPR/wave, so x is NOT register-resident: Phase A streams channel
// pairs (unroll 2 -> ~50 live VGPRs), Phase B re-reads x from L2 (lines are
// seconds-old in cache terms; NT output stores avoid evicting them).
// Grid 448 @ 2/CU = single scheduling round.
// ---------------------------------------------------------------------------
__global__ __launch_bounds__(1024, 8)   // min 8 waves/EU = 2 blocks/CU, VGPR cap 64
void pasa_main(const float* __restrict__ x,
               const v2f* __restrict__ wpk,
               const float* __restrict__ shift,
               float* __restrict__ out) {
    __shared__ float part[WAVES * KK * 64];   // 36 KB (x2 blocks = 72 KB/CU)
    __shared__ float sig[KK * 57];            // padded row stride

    // XCD swizzle: physical XCD = bid%8 = n; all rows of image n share one
    // XCD's L2 -> seam rows (2ho+1 = 2(ho+1)-1) are L2-hits, and Phase B
    // re-reads hit the lines Phase A just fetched.
    const int bid  = blockIdx.x;
    const int n    = bid & 7;
    const int ho   = bid >> 3;
    const int tid  = threadIdx.x;
    const int lane = tid & 63;
    const int wv   = __builtin_amdgcn_readfirstlane(tid >> 6);  // wave-uniform
    const int wo   = lane < WO ? lane : (WO - 1);               // clamp tail

    // Reflection-resolved source rows (top reflect only: -1 -> 1).
    const int r0 = (ho == 0) ? 1 : (2 * ho - 1);
    const int r1 = 2 * ho;
    const int r2 = 2 * ho + 1;

    const float* xn = x + (size_t)n * C * HW + 2 * wo;
    const int p0 = wv * PPW;   // first channel-pair of this wave

    // ---- Phase A: streamed partial sigma over the 4 channel pairs ---------
    v2f acc[KK];
#pragma unroll
    for (int k = 0; k < KK; ++k) acc[k] = (v2f){0.0f, 0.0f};

#pragma unroll 2
    for (int p = 0; p < PPW; ++p) {
        const float* xa = xn + (size_t)(2 * (p0 + p)) * HW;
        const float* xb = xa + HW;
        v2f va0 = *(const v2f*)(xa + r0 * W);
        v2f va1 = *(const v2f*)(xa + r1 * W);
        v2f va2 = *(const v2f*)(xa + r2 * W);
        v2f vb0 = *(const v2f*)(xb + r0 * W);
        v2f vb1 = *(const v2f*)(xb + r1 * W);
        v2f vb2 = *(const v2f*)(xb + r2 * W);
        const v2f* wb = wpk + (p0 + p) * 81;   // wave-uniform -> s_load
        v2f rowa[3] = { va0, va1, va2 };
        v2f rowb[3] = { vb0, vb1, vb2 };
#pragma unroll
        for (int kh = 0; kh < 3; ++kh) {
            v2f t1 = { rowa[kh].x, rowb[kh].x };
            v2f t2 = { rowa[kh].y, rowb[kh].y };
            v2f t0;
            t0.x = __shfl_up(t2.x, 1);   // lane0 keeps own = reflect(-1)=col1
            t0.y = __shfl_up(t2.y, 1);
            const v2f* wr = wb + kh * 27;
#pragma unroll
            for (int k = 0; k < KK; ++k)
                acc[k] = pkfma(t2, wr[3 * k + 2],
                          pkfma(t1, wr[3 * k + 1],
                          pkfma(t0, wr[3 * k + 0], acc[k])));
        }
    }

#pragma unroll
    for (int k = 0; k < KK; ++k)
        part[(wv * KK + k) * 64 + lane] = acc[k].x + acc[k].y;
    __syncthreads();

    // ---- Cross-wave reduce + BN shift + clamp -----------------------------
    if (tid < KK * WO) {
        const int k  = tid / WO;
        const int w_ = tid % WO;
        float s = 0.0f;
#pragma unroll
        for (int w2 = 0; w2 < WAVES; ++w2) s += part[(w2 * KK + k) * 64 + w_];
        s += shift[k];
        s = fmaxf(s, 1e-4f);
        sig[k * 57 + w_] = s;
    }
    __syncthreads();

    // ---- Normalize into registers (per-lane, lane = wo) -------------------
    float sg[KK];
    float tot = 0.0f;
#pragma unroll
    for (int k = 0; k < KK; ++k) { sg[k] = sig[k * 57 + wo]; tot += sg[k]; }
    const float inv = 1.0f / tot;
#pragma unroll
    for (int k = 0; k < KK; ++k) sg[k] *= inv;

    // ---- Phase B: re-read x from L2, apply adaptive filter, NT store ------
    float* on = out + ((size_t)n * C) * (HO * WO) + (size_t)ho * WO + lane;
#pragma unroll 2
    for (int p = 0; p < PPW; ++p) {
        const float* xa = xn + (size_t)(2 * (p0 + p)) * HW;
        const float* xb = xa + HW;
        v2f o = (v2f){0.0f, 0.0f};
#pragma unroll
        for (int kh = 0; kh < 3; ++kh) {
            const int rr = (kh == 0) ? r0 : (kh == 1) ? r1 : r2;
            v2f a = *(const v2f*)(xa + rr * W);
            v2f b = *(const v2f*)(xb + rr * W);
            v2f t1 = { a.x, b.x };
            v2f t2 = { a.y, b.y };
            v2f t0;
            t0.x = __shfl_up(t2.x, 1);
            t0.y = __shfl_up(t2.y, 1);
            v2f s0 = { sg[kh * 3 + 0], sg[kh * 3 + 0] };
            v2f s1 = { sg[kh * 3 + 1], sg[kh * 3 + 1] };
            v2f s2 = { sg[kh * 3 + 2], sg[kh * 3 + 2] };
            o = pkfma(t2, s2, pkfma(t1, s1, pkfma(t0, s0, o)));
        }
        if (lane < WO) {
            const int ci = 2 * (p0 + p);
            __builtin_nontemporal_store(o.x, on + (size_t)ci * (HO * WO));
            __builtin_nontemporal_store(o.y, on + (size_t)(ci + 1) * (HO * WO));
        }
    }
}

extern "C" void kernel_launch(void* const* d_in, const int* in_sizes, int n_in,
                              void* d_out, int out_size, void* d_ws, size_t ws_size,
                              hipStream_t stream) {
    const float* x   = (const float*)d_in[0];
    const float* cw  = (const float*)d_in[1];
    const float* bw  = (const float*)d_in[2];
    const float* bb  = (const float*)d_in[3];
    const float* bm  = (const float*)d_in[4];
    const float* bv  = (const float*)d_in[5];
    float* ws  = (float*)d_ws;
    float* out = (float*)d_out;

    const int prep_elems = WPK_ELEMS + KK;
    pasa_prep<<<(prep_elems + 255) / 256, 256, 0, stream>>>(cw, bw, bb, bm, bv, ws);
    pasa_main<<<NB * HO, 1024, 0, stream>>>(x, (const v2f*)ws,
                                            ws + SHIFT_OFF, out);
}